// Round 2
// baseline (60.315 us; speedup 1.0000x reference)
//
#include <hip/hip_runtime.h>
#include <hip/hip_bf16.h>
#include <stdint.h>

#define B_  256
#define T_  1024
#define F_  16
#define N_  1024

typedef short bf16x8 __attribute__((ext_vector_type(8)));
typedef float f32x4  __attribute__((ext_vector_type(4)));

static __device__ __forceinline__ unsigned short f2bf(float x) {
  unsigned u = __builtin_bit_cast(unsigned, x);
  u += 0x7fffu + ((u >> 16) & 1u);
  return (unsigned short)(u >> 16);
}
static __device__ __forceinline__ float bf2f(unsigned short h) {
  unsigned u = ((unsigned)h) << 16;
  return __builtin_bit_cast(float, u);
}

// ---- pass 1: x[b][t][f] fp32 -> At[f][b][t] bf16 ----
__global__ __launch_bounds__(256) void prep_kernel(const float* __restrict__ x,
                                                   unsigned short* __restrict__ At) {
  __shared__ float tile[64 * 17];
  const int b = blockIdx.x, tid = threadIdx.x;
  const float* xb = x + (size_t)b * (T_ * F_);
  const int tld = tid >> 2, fb = (tid & 3) * 4;   // load mapping
  const int fw  = tid >> 4, ti = tid & 15;        // write mapping
  for (int tc = 0; tc < 16; ++tc) {
    float4 v = *(const float4*)(xb + tc * 1024 + tid * 4);
    tile[tld * 17 + fb + 0] = v.x;
    tile[tld * 17 + fb + 1] = v.y;
    tile[tld * 17 + fb + 2] = v.z;
    tile[tld * 17 + fb + 3] = v.w;
    __syncthreads();
    unsigned short o0 = f2bf(tile[(ti * 4 + 0) * 17 + fw]);
    unsigned short o1 = f2bf(tile[(ti * 4 + 1) * 17 + fw]);
    unsigned short o2 = f2bf(tile[(ti * 4 + 2) * 17 + fw]);
    unsigned short o3 = f2bf(tile[(ti * 4 + 3) * 17 + fw]);
    uint2 pk;
    pk.x = (unsigned)o0 | ((unsigned)o1 << 16);
    pk.y = (unsigned)o2 | ((unsigned)o3 << 16);
    *(uint2*)(At + ((size_t)fw * B_ + b) * T_ + tc * 64 + ti * 4) = pk;
    __syncthreads();
  }
}

// ---- pass 2: fused GEMM: acc[b,n] = sum_t x_bf16[b,t,f] * V[f,t,n] ----
// V[t] = c1*TW[t] + c2*RW[t] + 0.5*(TW[t-1] - RW[t-1]);  c1,c2 = (0.5,0.5) for
// t < T-1, (1,0) at t = T-1; prev-term dropped at t = 0.
// TMPOUT=1: write bf16 tmp[F][B][N] (coalesced; pass 3 transposes).
// TMPOUT=0: direct scattered fp32 store to out[B][N][F] (ws-too-small fallback).
template <int TMPOUT>
__global__ __launch_bounds__(256) void gemm_kernel(const unsigned short* __restrict__ At,
                                                   const float* __restrict__ TW,
                                                   const float* __restrict__ RW,
                                                   const float* __restrict__ tb,
                                                   const float* __restrict__ rb,
                                                   float* __restrict__ out,
                                                   unsigned short* __restrict__ tmp) {
  __shared__ float rawT[64 * 36];           // padded rows (36 words) for even LDS banking
  __shared__ float rawR[64 * 36];
  __shared__ unsigned short vT[32 * 72];    // V^T bf16, [n][t], padded rows
  __shared__ float prevT[2][32], prevR[2][32];

  const int tid = threadIdx.x;
  const int f  = blockIdx.x >> 5;
  const int n0 = (blockIdx.x & 31) * 32;
  const int w = tid >> 6, l = tid & 63;
  const int lrow = l & 15, lg = l >> 4;

  const float* TWf = TW + (size_t)f * (T_ * N_) + n0;
  const float* RWf = RW + (size_t)f * (T_ * N_) + n0;
  const unsigned short* Af = At + (size_t)f * (B_ * T_);

  const int srow0 = tid >> 3;          // rows 0..31
  const int srow1 = 32 + (tid >> 3);   // rows 32..63
  const int sc    = (tid & 7) * 4;     // col (floats)

  const int vn = tid & 31, strip = tid >> 5;

  f32x4 acc[4][2];
#pragma unroll
  for (int m = 0; m < 4; ++m)
#pragma unroll
    for (int nn = 0; nn < 2; ++nn)
      acc[m][nn] = (f32x4){0.f, 0.f, 0.f, 0.f};

  // prologue: prefetch tile 0 weights + A-frags
  float4 rT0 = *(const float4*)(TWf + (size_t)srow0 * N_ + sc);
  float4 rT1 = *(const float4*)(TWf + (size_t)srow1 * N_ + sc);
  float4 rR0 = *(const float4*)(RWf + (size_t)srow0 * N_ + sc);
  float4 rR1 = *(const float4*)(RWf + (size_t)srow1 * N_ + sc);
  bf16x8 afrag[2][2][4];
#pragma unroll
  for (int ks = 0; ks < 2; ++ks)
#pragma unroll
    for (int m = 0; m < 4; ++m)
      afrag[0][ks][m] = *(const bf16x8*)(Af + (size_t)(w * 64 + m * 16 + lrow) * T_ + ks * 32 + lg * 8);

#pragma unroll
  for (int kt = 0; kt < 16; ++kt) {
    const int k0 = kt * 64;
    __syncthreads();   // previous tile's vT / raw LDS fully consumed
    // commit staged weight regs -> LDS
    *(float4*)&rawT[srow0 * 36 + sc] = rT0;
    *(float4*)&rawT[srow1 * 36 + sc] = rT1;
    *(float4*)&rawR[srow0 * 36 + sc] = rR0;
    *(float4*)&rawR[srow1 * 36 + sc] = rR1;
    // prefetch next tile (weights + A-frags) while this tile is processed
    if (kt < 15) {
      const float* TWn = TWf + (size_t)(k0 + 64) * N_;
      const float* RWn = RWf + (size_t)(k0 + 64) * N_;
      rT0 = *(const float4*)(TWn + (size_t)srow0 * N_ + sc);
      rT1 = *(const float4*)(TWn + (size_t)srow1 * N_ + sc);
      rR0 = *(const float4*)(RWn + (size_t)srow0 * N_ + sc);
      rR1 = *(const float4*)(RWn + (size_t)srow1 * N_ + sc);
#pragma unroll
      for (int ks = 0; ks < 2; ++ks)
#pragma unroll
        for (int m = 0; m < 4; ++m)
          afrag[(kt + 1) & 1][ks][m] =
              *(const bf16x8*)(Af + (size_t)(w * 64 + m * 16 + lrow) * T_ + (k0 + 64) + ks * 32 + lg * 8);
    }
    __syncthreads();   // raw LDS ready
    // ---- V-compute (32 n-lanes x 8 t-strips per 64-row tile) ----
    {
      float ptw, prw;
      if (strip == 0) { ptw = prevT[(kt & 1) ^ 1][vn]; prw = prevR[(kt & 1) ^ 1][vn]; }
      else            { ptw = rawT[(strip * 8 - 1) * 36 + vn]; prw = rawR[(strip * 8 - 1) * 36 + vn]; }
      unsigned pk[4];
      unsigned lo = 0;
      float tw = 0.f, rw = 0.f;
#pragma unroll
      for (int i = 0; i < 8; ++i) {
        const int t = strip * 8 + i, tg = k0 + t;
        tw = rawT[t * 36 + vn]; rw = rawR[t * 36 + vn];
        const float c1 = (tg < T_ - 1) ? 0.5f : 1.0f;
        const float c2 = (tg < T_ - 1) ? 0.5f : 0.0f;
        const float pterm = (tg >= 1) ? 0.5f * (ptw - prw) : 0.0f;
        const unsigned short us = f2bf(c1 * tw + c2 * rw + pterm);
        if ((i & 1) == 0) lo = us; else pk[i >> 1] = lo | ((unsigned)us << 16);
        ptw = tw; prw = rw;
      }
      uint4 q; q.x = pk[0]; q.y = pk[1]; q.z = pk[2]; q.w = pk[3];
      *(uint4*)&vT[vn * 72 + strip * 8] = q;
      if (strip == 7) { prevT[kt & 1][vn] = tw; prevR[kt & 1][vn] = rw; }
    }
    __syncthreads();   // vT ready
    // ---- MFMA ----
#pragma unroll
    for (int ks = 0; ks < 2; ++ks) {
      bf16x8 bfrag[2];
#pragma unroll
      for (int nn = 0; nn < 2; ++nn)
        bfrag[nn] = *(const bf16x8*)&vT[(nn * 16 + lrow) * 72 + ks * 32 + lg * 8];
#pragma unroll
      for (int m = 0; m < 4; ++m)
#pragma unroll
        for (int nn = 0; nn < 2; ++nn)
          acc[m][nn] = __builtin_amdgcn_mfma_f32_16x16x32_bf16(afrag[kt & 1][ks][m], bfrag[nn], acc[m][nn], 0, 0, 0);
    }
  }

  // ---- epilogue: bias + store ----
  float bsum[2];
#pragma unroll
  for (int nn = 0; nn < 2; ++nn) {
    const int n = n0 + nn * 16 + lrow;
    bsum[nn] = tb[f * N_ + n] + rb[f * N_ + n];
  }
#pragma unroll
  for (int m = 0; m < 4; ++m)
#pragma unroll
    for (int nn = 0; nn < 2; ++nn) {
      const int n = n0 + nn * 16 + lrow;
#pragma unroll
      for (int j = 0; j < 4; ++j) {
        const int brow = w * 64 + m * 16 + lg * 4 + j;
        const float v = acc[m][nn][j] + bsum[nn];
        if (TMPOUT) {
          tmp[((size_t)f * B_ + brow) * N_ + n] = f2bf(v);          // 2B, 16-lane 32B segments
        } else {
          out[((size_t)brow * N_ + n) * F_ + f] = v;                // scattered fallback
        }
      }
    }
}

// ---- pass 3: tmp[F][B][N] bf16 -> out[B][N][F] fp32, coalesced both sides ----
__global__ __launch_bounds__(256) void untile_kernel(const unsigned short* __restrict__ tmp,
                                                     float* __restrict__ out) {
  __shared__ unsigned short ld[16 * 1048];   // [f][n], padded pitch (2096B, 16B-aligned)
  const int b = blockIdx.x, tid = threadIdx.x;
#pragma unroll
  for (int it = 0; it < 8; ++it) {
    const int idx = it * 256 + tid;
    const int f = idx >> 7, c = idx & 127;
    uint4 v = *(const uint4*)(tmp + ((size_t)f * B_ + b) * N_ + c * 8);
    *(uint4*)&ld[f * 1048 + c * 8] = v;
  }
  __syncthreads();
  float* ob = out + (size_t)b * (N_ * F_);
#pragma unroll
  for (int it = 0; it < 16; ++it) {
    const int g = it * 256 + tid;
    const int n = g >> 2, f0 = (g & 3) * 4;
    float4 o;
    o.x = bf2f(ld[(f0 + 0) * 1048 + n]);
    o.y = bf2f(ld[(f0 + 1) * 1048 + n]);
    o.z = bf2f(ld[(f0 + 2) * 1048 + n]);
    o.w = bf2f(ld[(f0 + 3) * 1048 + n]);
    *(float4*)(ob + n * F_ + f0) = o;
  }
}

extern "C" void kernel_launch(void* const* d_in, const int* in_sizes, int n_in,
                              void* d_out, int out_size, void* d_ws, size_t ws_size,
                              hipStream_t stream) {
  const float* x  = (const float*)d_in[0];
  const float* TW = (const float*)d_in[8];
  const float* tb = (const float*)d_in[9];
  const float* RW = (const float*)d_in[10];
  const float* rb = (const float*)d_in[11];
  float* out = (float*)d_out;

  unsigned short* At = (unsigned short*)d_ws;                 // 16*256*1024*2 = 8 MB
  const size_t atBytes  = (size_t)F_ * B_ * T_ * sizeof(unsigned short);
  const size_t tmpBytes = (size_t)F_ * B_ * N_ * sizeof(unsigned short);

  prep_kernel<<<256, 256, 0, stream>>>(x, At);
  if (ws_size >= atBytes + tmpBytes) {
    unsigned short* tmp = (unsigned short*)((char*)d_ws + atBytes);
    gemm_kernel<1><<<512, 256, 0, stream>>>(At, TW, RW, tb, rb, out, tmp);
    untile_kernel<<<256, 256, 0, stream>>>(tmp, out);
  } else {
    gemm_kernel<0><<<512, 256, 0, stream>>>(At, TW, RW, tb, rb, out, nullptr);
  }
}

// Round 4
// 44.361 us; speedup vs baseline: 1.3596x; 1.3596x over previous
//
#include <hip/hip_runtime.h>
#include <hip/hip_bf16.h>
#include <stdint.h>

#define B_  256
#define T_  1024
#define F_  16
#define N_  1024

typedef short bf16x8 __attribute__((ext_vector_type(8)));
typedef float f32x4  __attribute__((ext_vector_type(4)));

static __device__ __forceinline__ unsigned short f2bf(float x) {
  unsigned u = __builtin_bit_cast(unsigned, x);
  u += 0x7fffu + ((u >> 16) & 1u);
  return (unsigned short)(u >> 16);
}
static __device__ __forceinline__ float bf2f(unsigned short h) {
  unsigned u = ((unsigned)h) << 16;
  return __builtin_bit_cast(float, u);
}

// ---- pass 1: x[b][t][f] fp32 -> At2 fragment layout bf16 ----
// At2 element (f,b,k) at ((f*32+kc)*16+rb)*512 + lane*8 + j, where
// kc=k>>5, rb=b>>4, lane=((k>>3)&3)*16 + (b&15), j=k&7.
// Gemm A-load for (w,m,ks,kt): one contiguous 1KB wave read.
__global__ __launch_bounds__(256) void prep2_kernel(const float* __restrict__ x,
                                                    unsigned short* __restrict__ At2) {
  __shared__ unsigned short ld[16 * 1028];   // [b_local][t_local*16+f], pitch 1028
  const int rb = blockIdx.x >> 4, tc = blockIdx.x & 15;
  const int tid = threadIdx.x;
  const int tl = tid >> 2;            // t-local 0..63
  const int f4 = (tid & 3) * 4;       // f quad
  // read phase: one b-row per iteration, fully coalesced
#pragma unroll
  for (int i = 0; i < 16; ++i) {
    const float* src = x + (((size_t)(rb * 16 + i) * T_) + tc * 64 + tl) * F_ + f4;
    float4 v = *(const float4*)src;
    uint2 pk;
    pk.x = (unsigned)f2bf(v.x) | ((unsigned)f2bf(v.y) << 16);
    pk.y = (unsigned)f2bf(v.z) | ((unsigned)f2bf(v.w) << 16);
    *(uint2*)&ld[i * 1028 + tl * 16 + f4] = pk;
  }
  __syncthreads();
  // write phase: per iteration, each wave emits one contiguous 1KB chunk
  const int w = tid >> 6, l = tid & 63;
#pragma unroll
  for (int it = 0; it < 8; ++it) {
    const int c = it * 4 + w;          // 0..31 = (f, kcl)
    const int f = c >> 1, kcl = c & 1;
    unsigned short t16[8];
#pragma unroll
    for (int j = 0; j < 8; ++j)
      t16[j] = ld[(l & 15) * 1028 + (kcl * 32 + ((l >> 4) * 8) + j) * 16 + f];
    uint4 q;
    q.x = (unsigned)t16[0] | ((unsigned)t16[1] << 16);
    q.y = (unsigned)t16[2] | ((unsigned)t16[3] << 16);
    q.z = (unsigned)t16[4] | ((unsigned)t16[5] << 16);
    q.w = (unsigned)t16[6] | ((unsigned)t16[7] << 16);
    *(uint4*)(At2 + (((size_t)(f * 32 + tc * 2 + kcl) * 16 + rb) << 9) + l * 8) = q;
  }
}

// ---- pass 2: fused GEMM: acc[b,n] = sum_t x_bf16[b,t,f] * V[f,t,n] ----
// V[t] = c1*TW[t] + c2*RW[t] + 0.5*(TW[t-1] - RW[t-1]);  c1,c2 = (0.5,0.5) for
// t < T-1, (1,0) at t = T-1; prev-term dropped at t = 0.
template <int TMPOUT>
__global__ __launch_bounds__(256) void gemm_kernel(const unsigned short* __restrict__ At2,
                                                   const float* __restrict__ TW,
                                                   const float* __restrict__ RW,
                                                   const float* __restrict__ tb,
                                                   const float* __restrict__ rb,
                                                   float* __restrict__ out,
                                                   unsigned short* __restrict__ tmp) {
  __shared__ float rawT[64 * 36];           // padded rows (36 words) for even LDS banking
  __shared__ float rawR[64 * 36];
  __shared__ unsigned short vT[32 * 72];    // V^T bf16, [n][t], padded rows
  __shared__ float prevT[2][32], prevR[2][32];

  const int tid = threadIdx.x;
  // XCD chunk swizzle: 512 blocks, 8 XCDs -> 64 consecutive logical ids per XCD,
  // so all 32 n-tiles of an f-panel share one XCD's L2 (At2 panel read once/XCD).
  const int bid = (blockIdx.x & 7) * 64 + (blockIdx.x >> 3);
  const int f  = bid >> 5;
  const int n0 = (bid & 31) * 32;
  const int w = tid >> 6, l = tid & 63;
  const int lrow = l & 15, lg = l >> 4;

  const float* TWf = TW + (size_t)f * (T_ * N_) + n0;
  const float* RWf = RW + (size_t)f * (T_ * N_) + n0;
  const unsigned short* Af2 = At2 + ((size_t)f * 32 * 16 * 512);

  const int srow0 = tid >> 3;          // rows 0..31
  const int srow1 = 32 + (tid >> 3);   // rows 32..63
  const int sc    = (tid & 7) * 4;     // col (floats)

  const int vn = tid & 31, strip = tid >> 5;

  f32x4 acc[4][2];
#pragma unroll
  for (int m = 0; m < 4; ++m)
#pragma unroll
    for (int nn = 0; nn < 2; ++nn)
      acc[m][nn] = (f32x4){0.f, 0.f, 0.f, 0.f};

  // prologue: prefetch tile 0 weights + A-frags (coalesced 1KB wave loads)
  float4 rT0 = *(const float4*)(TWf + (size_t)srow0 * N_ + sc);
  float4 rT1 = *(const float4*)(TWf + (size_t)srow1 * N_ + sc);
  float4 rR0 = *(const float4*)(RWf + (size_t)srow0 * N_ + sc);
  float4 rR1 = *(const float4*)(RWf + (size_t)srow1 * N_ + sc);
  bf16x8 afrag[2][2][4];
#pragma unroll
  for (int ks = 0; ks < 2; ++ks)
#pragma unroll
    for (int m = 0; m < 4; ++m)
      afrag[0][ks][m] = *(const bf16x8*)(Af2 + (((size_t)(ks * 16) + (w * 4 + m)) << 9) + l * 8);

#pragma unroll
  for (int kt = 0; kt < 16; ++kt) {
    const int k0 = kt * 64;
    __syncthreads();   // previous tile's vT / raw LDS fully consumed
    // commit staged weight regs -> LDS
    *(float4*)&rawT[srow0 * 36 + sc] = rT0;
    *(float4*)&rawT[srow1 * 36 + sc] = rT1;
    *(float4*)&rawR[srow0 * 36 + sc] = rR0;
    *(float4*)&rawR[srow1 * 36 + sc] = rR1;
    // prefetch next tile (weights + A-frags) while this tile is processed
    if (kt < 15) {
      const float* TWn = TWf + (size_t)(k0 + 64) * N_;
      const float* RWn = RWf + (size_t)(k0 + 64) * N_;
      rT0 = *(const float4*)(TWn + (size_t)srow0 * N_ + sc);
      rT1 = *(const float4*)(TWn + (size_t)srow1 * N_ + sc);
      rR0 = *(const float4*)(RWn + (size_t)srow0 * N_ + sc);
      rR1 = *(const float4*)(RWn + (size_t)srow1 * N_ + sc);
#pragma unroll
      for (int ks = 0; ks < 2; ++ks)
#pragma unroll
        for (int m = 0; m < 4; ++m)
          afrag[(kt + 1) & 1][ks][m] =
              *(const bf16x8*)(Af2 + (((size_t)((kt + 1) * 2 + ks) * 16 + (w * 4 + m)) << 9) + l * 8);
    }
    __syncthreads();   // raw LDS ready
    // ---- V-compute (32 n-lanes x 8 t-strips per 64-row tile) ----
    {
      float ptw, prw;
      if (strip == 0) { ptw = prevT[(kt & 1) ^ 1][vn]; prw = prevR[(kt & 1) ^ 1][vn]; }
      else            { ptw = rawT[(strip * 8 - 1) * 36 + vn]; prw = rawR[(strip * 8 - 1) * 36 + vn]; }
      unsigned pk[4];
      unsigned lo = 0;
      float tw = 0.f, rw = 0.f;
#pragma unroll
      for (int i = 0; i < 8; ++i) {
        const int t = strip * 8 + i, tg = k0 + t;
        tw = rawT[t * 36 + vn]; rw = rawR[t * 36 + vn];
        const float c1 = (tg < T_ - 1) ? 0.5f : 1.0f;
        const float c2 = (tg < T_ - 1) ? 0.5f : 0.0f;
        const float pterm = (tg >= 1) ? 0.5f * (ptw - prw) : 0.0f;
        const unsigned short us = f2bf(c1 * tw + c2 * rw + pterm);
        if ((i & 1) == 0) lo = us; else pk[i >> 1] = lo | ((unsigned)us << 16);
        ptw = tw; prw = rw;
      }
      uint4 q; q.x = pk[0]; q.y = pk[1]; q.z = pk[2]; q.w = pk[3];
      *(uint4*)&vT[vn * 72 + strip * 8] = q;
      if (strip == 7) { prevT[kt & 1][vn] = tw; prevR[kt & 1][vn] = rw; }
    }
    __syncthreads();   // vT ready
    // ---- MFMA ----
#pragma unroll
    for (int ks = 0; ks < 2; ++ks) {
      bf16x8 bfrag[2];
#pragma unroll
      for (int nn = 0; nn < 2; ++nn)
        bfrag[nn] = *(const bf16x8*)&vT[(nn * 16 + lrow) * 72 + ks * 32 + lg * 8];
#pragma unroll
      for (int m = 0; m < 4; ++m)
#pragma unroll
        for (int nn = 0; nn < 2; ++nn)
          acc[m][nn] = __builtin_amdgcn_mfma_f32_16x16x32_bf16(afrag[kt & 1][ks][m], bfrag[nn], acc[m][nn], 0, 0, 0);
    }
  }

  // ---- epilogue: bias + store ----
  float bsum[2];
#pragma unroll
  for (int nn = 0; nn < 2; ++nn) {
    const int n = n0 + nn * 16 + lrow;
    bsum[nn] = tb[f * N_ + n] + rb[f * N_ + n];
  }
#pragma unroll
  for (int m = 0; m < 4; ++m)
#pragma unroll
    for (int nn = 0; nn < 2; ++nn) {
      const int n = n0 + nn * 16 + lrow;
#pragma unroll
      for (int j = 0; j < 4; ++j) {
        const int brow = w * 64 + m * 16 + lg * 4 + j;
        const float v = acc[m][nn][j] + bsum[nn];
        if (TMPOUT) {
          tmp[((size_t)f * B_ + brow) * N_ + n] = f2bf(v);          // coalesced 32B segments
        } else {
          out[((size_t)brow * N_ + n) * F_ + f] = v;                // scattered fallback
        }
      }
    }
}

// ---- pass 3: tmp[F][B][N] bf16 -> out[B][N][F] fp32, coalesced both sides ----
__global__ __launch_bounds__(256) void untile_kernel(const unsigned short* __restrict__ tmp,
                                                     float* __restrict__ out) {
  __shared__ unsigned short ld[16 * 1048];   // [f][n], padded pitch
  const int b = blockIdx.x, tid = threadIdx.x;
#pragma unroll
  for (int it = 0; it < 8; ++it) {
    const int idx = it * 256 + tid;
    const int f = idx >> 7, c = idx & 127;
    uint4 v = *(const uint4*)(tmp + ((size_t)f * B_ + b) * N_ + c * 8);
    *(uint4*)&ld[f * 1048 + c * 8] = v;
  }
  __syncthreads();
  float* ob = out + (size_t)b * (N_ * F_);
#pragma unroll
  for (int it = 0; it < 16; ++it) {
    const int g = it * 256 + tid;
    const int n = g >> 2, f0 = (g & 3) * 4;
    float4 o;
    o.x = bf2f(ld[(f0 + 0) * 1048 + n]);
    o.y = bf2f(ld[(f0 + 1) * 1048 + n]);
    o.z = bf2f(ld[(f0 + 2) * 1048 + n]);
    o.w = bf2f(ld[(f0 + 3) * 1048 + n]);
    *(float4*)(ob + n * F_ + f0) = o;
  }
}

extern "C" void kernel_launch(void* const* d_in, const int* in_sizes, int n_in,
                              void* d_out, int out_size, void* d_ws, size_t ws_size,
                              hipStream_t stream) {
  const float* x  = (const float*)d_in[0];
  const float* TW = (const float*)d_in[8];
  const float* tb = (const float*)d_in[9];
  const float* RW = (const float*)d_in[10];
  const float* rb = (const float*)d_in[11];
  float* out = (float*)d_out;

  unsigned short* At2 = (unsigned short*)d_ws;                // 8 MB
  const size_t atBytes  = (size_t)F_ * B_ * T_ * sizeof(unsigned short);
  const size_t tmpBytes = (size_t)F_ * B_ * N_ * sizeof(unsigned short);

  prep2_kernel<<<256, 256, 0, stream>>>(x, At2);
  if (ws_size >= atBytes + tmpBytes) {
    unsigned short* tmp = (unsigned short*)((char*)d_ws + atBytes);
    gemm_kernel<1><<<512, 256, 0, stream>>>(At2, TW, RW, tb, rb, out, tmp);
    untile_kernel<<<256, 256, 0, stream>>>(tmp, out);
  } else {
    gemm_kernel<0><<<512, 256, 0, stream>>>(At2, TW, RW, tb, rb, out, nullptr);
  }
}